// Round 12
// baseline (65.516 us; speedup 1.0000x reference)
//
#include <hip/hip_runtime.h>

namespace {
constexpr int kM = 4, kJ = 2, kI = 3, kL = 2, kW = 9;
constexpr float kInvLn2 = 1.4426950408889634f;
constexpr int kRep = 3;   // DIAGNOSTIC: compute runs 3x (loads/stores 1x)

typedef float v2f __attribute__((ext_vector_type(2)));  // -> v_pk_*_f32

__device__ __forceinline__ float fexp2(float x) { return __builtin_amdgcn_exp2f(x); }

// R10 body + REP-loop probe. sdp layout (72 floats), per m (16 at m*16),
// j-packed {j0,j1}: [c0, c1, w0n, w1n, C00, C01, C10, C11];
// msN = w0n*(s0-c0)^2 + w1n*(s1-c1)^2, w*n = -(1-g*)/ln2; D[m][l] at 64+m*2+l.
__global__ __launch_bounds__(256, 4) void algelogic_probe(
    const float* __restrict__ state,
    const float* __restrict__ constants,
    const float* __restrict__ gammas,
    const float* __restrict__ W_body,
    const float* __restrict__ b_body,
    const float* __restrict__ W_head,
    const float* __restrict__ b_head,
    float* __restrict__ out) {
  __shared__ float sdp[72];
  const int t = threadIdx.x;
  const int b = blockIdx.x * 256 + t;

  // state loads issued first (in flight during the fold)
  const float2* sr = reinterpret_cast<const float2*>(state) + (size_t)b * kW;
  v2f s[kW];
#pragma unroll
  for (int w = 0; w < kW; ++w) {
    const float2 v = sr[w];
    v2f x; x.x = v.x; x.y = v.y;
    s[w] = x;
  }

  // param fold: wave0 lanes 0-7 coeffs+C; wave1 lanes 0-3 D
  if (t < 8) {
    const int mj = t, m = t >> 1, j = t & 1;
    const float g0 = fminf(fmaxf(gammas[mj * kL + 0], 0.f), 1.f);
    const float g1 = fminf(fmaxf(gammas[mj * kL + 1], 0.f), 1.f);
    const float w0 = 1.f - g0, w1 = 1.f - g1;
    const float c0 = constants[mj * kL + 0], c1 = constants[mj * kL + 1];
    const float gavg = 0.5f * (g0 + g1);
    float* base = sdp + m * 16;
    base[0 * 2 + j] = c0;
    base[1 * 2 + j] = c1;
    base[2 * 2 + j] = -w0 * kInvLn2;
    base[3 * 2 + j] = -w1 * kInvLn2;
#pragma unroll
    for (int l = 0; l < kL; ++l)
#pragma unroll
      for (int lp = 0; lp < kL; ++lp) {
        float acc = 0.f;
#pragma unroll
        for (int i = 0; i < kI; ++i)
          acc += W_head[(m * kL + l) * kI + i] * W_body[(mj * kI + i) * kL + lp];
        base[(4 + l * kL + lp) * 2 + j] = gavg * acc;
      }
  } else if (t >= 64 && t < 68) {
    const int m = t - 64;
#pragma unroll
    for (int l = 0; l < kL; ++l) {
      float d = b_head[m * kL + l];
#pragma unroll
      for (int j = 0; j < kJ; ++j) {
        const int mj = m * kJ + j;
        const float g0 = fminf(fmaxf(gammas[mj * kL + 0], 0.f), 1.f);
        const float g1 = fminf(fmaxf(gammas[mj * kL + 1], 0.f), 1.f);
        const float gavg = 0.5f * (g0 + g1);
        float acc = 0.f;
#pragma unroll
        for (int i = 0; i < kI; ++i)
          acc += W_head[(m * kL + l) * kI + i] * b_body[mj * kI + i];
        d += gavg * acc;
      }
      sdp[64 + m * kL + l] = d;
    }
  }
  __syncthreads();

  float CsA = 0.f, X0A = 0.f, X1A = 0.f, KA = 0.f;

#pragma unroll 1
  for (int rep = 0; rep < kRep; ++rep) {   // runtime rep: passes 1,2 kept live
    float Cs = 0.f, X0 = 0.f, X1 = 0.f, K = 0.f;
#pragma unroll
    for (int m = 0; m < kM; ++m) {
      const float* P = sdp + m * 16;
      v2f c0;  c0.x = P[0];  c0.y = P[1];
      v2f c1;  c1.x = P[2];  c1.y = P[3];
      v2f w0n; w0n.x = P[4]; w0n.y = P[5];
      v2f w1n; w1n.x = P[6]; w1n.y = P[7];

      v2f psum = {1e-35f, 1e-35f};
      v2f pb0 = {0.f, 0.f}, pb1 = {0.f, 0.f}, pmq = {0.f, 0.f};
#pragma unroll
      for (int w = 0; w < kW; ++w) {
        const float sx = s[w].x, sy = s[w].y;
        const v2f d0 = sx - c0;
        const v2f d1 = sy - c1;
        v2f msN = (d0 * d0) * w0n;
        msN += (d1 * d1) * w1n;
        v2f e; e.x = fexp2(msN.x); e.y = fexp2(msN.y);
        psum += e;
        pb0 += e * sx;
        pb1 += e * sy;
        pmq += e * msN;
      }

      v2f rinv;
      rinv.x = __builtin_amdgcn_rcpf(psum.x);
      rinv.y = __builtin_amdgcn_rcpf(psum.y);
      const v2f bb0 = pb0 * rinv, bb1 = pb1 * rinv;
      const v2f mqv = pmq * rinv;
      const float conf = fexp2(mqv.x + mqv.y);

      v2f C00; C00.x = P[8];  C00.y = P[9];
      v2f C01; C01.x = P[10]; C01.y = P[11];
      v2f C10; C10.x = P[12]; C10.y = P[13];
      v2f C11; C11.x = P[14]; C11.y = P[15];
      const v2f t0 = C00 * bb0 + C01 * bb1;
      const v2f t1 = C10 * bb0 + C11 * bb1;
      const float r0 = sdp[64 + m * 2 + 0] + t0.x + t0.y;
      const float r1 = sdp[64 + m * 2 + 1] + t1.x + t1.y;

      Cs += conf;
      X0 = fmaf(conf, r0, X0);
      X1 = fmaf(conf, r1, X1);
      K = fmaf(conf, fmaf(r0, r0, r1 * r1), K);
    }
    if (rep == 0) {
      CsA = Cs; X0A = X0; X1A = X1; KA = K;
    } else {
      // keep redundant passes live without affecting output (rule #17)
      asm volatile("" :: "v"(Cs), "v"(X0), "v"(X1), "v"(K));
    }
  }

  const float X02 = 2.f * X0A, X12 = 2.f * X1A;
  float* orow = out + (size_t)b * kW;
#pragma unroll
  for (int w = 0; w < kW; ++w) {
    const v2f q = s[w] * s[w];
    orow[w] = fmaf(X02, s[w].x, fmaf(X12, s[w].y, fmaf(-CsA, q.x + q.y, -KA)));
  }
}
}  // namespace

extern "C" void kernel_launch(void* const* d_in, const int* in_sizes, int n_in,
                              void* d_out, int out_size, void* d_ws, size_t ws_size,
                              hipStream_t stream) {
  const float* state     = (const float*)d_in[0];
  const float* constants = (const float*)d_in[1];
  const float* gammas    = (const float*)d_in[2];
  const float* W_body    = (const float*)d_in[3];
  const float* b_body    = (const float*)d_in[4];
  const float* W_head    = (const float*)d_in[5];
  const float* b_head    = (const float*)d_in[6];
  float* out = (float*)d_out;

  const int B = in_sizes[0] / (kW * kL);   // 1048576
  hipLaunchKernelGGL(algelogic_probe, dim3(B / 256), dim3(256), 0, stream,
                     state, constants, gammas, W_body, b_body, W_head, b_head, out);
}

// Round 13
// 30.577 us; speedup vs baseline: 2.1427x; 2.1427x over previous
//
#include <hip/hip_runtime.h>

namespace {
constexpr int kM = 4, kJ = 2, kI = 3, kL = 2, kW = 9;
constexpr float kInvLn2 = 1.4426950408889634f;

typedef float v2f __attribute__((ext_vector_type(2)));  // -> v_pk_*_f32

__device__ __forceinline__ float fexp2(float x) { return __builtin_amdgcn_exp2f(x); }

// Fused kernel. sdp layout (80 floats), per m (18 floats at m*18),
// j-packed {j0,j1} pairs:
//   [An, B0n, B1n, w0n, w1n, C00, C01, C10, C11]
// expanded-Horner match score (negated, log2-scaled):
//   msN = An + sx*(B0n + w0n*sx) + sy*(B1n + w1n*sy)  == -ms/ln2  (<= 0)
// C (head∘body, gavg-folded) unscaled. D[m][l] at 72 + m*2 + l.
//
// KEY (from R12 probe): v2f math was scalarizing because pk ops read TWO
// wave-uniform (SGPR) operands — illegal (1 SGPR max per VALU instr).
// Fix: coerce the ADDEND params (An,B0n,B1n) into VGPRs via asm; the
// multiplier params (w0n,w1n,C**) remain the single legal SGPR source.
__global__ __launch_bounds__(256, 4) void algelogic_one(
    const float* __restrict__ state,
    const float* __restrict__ constants,
    const float* __restrict__ gammas,
    const float* __restrict__ W_body,
    const float* __restrict__ b_body,
    const float* __restrict__ W_head,
    const float* __restrict__ b_head,
    float* __restrict__ out) {
  __shared__ float sdp[80];
  const int t = threadIdx.x;
  const int b = blockIdx.x * 256 + t;

  // ---- state loads issued first (in flight during the fold) ----
  const float2* sr = reinterpret_cast<const float2*>(state) + (size_t)b * kW;
  v2f s[kW];
#pragma unroll
  for (int w = 0; w < kW; ++w) {
    const float2 v = sr[w];
    v2f x; x.x = v.x; x.y = v.y;
    s[w] = x;
  }

  // ---- param fold: wave0 lanes 0-7 coeffs+C; wave1 lanes 0-3 D ----
  if (t < 8) {
    const int mj = t, m = t >> 1, j = t & 1;
    const float g0 = fminf(fmaxf(gammas[mj * kL + 0], 0.f), 1.f);
    const float g1 = fminf(fmaxf(gammas[mj * kL + 1], 0.f), 1.f);
    const float w0 = 1.f - g0, w1 = 1.f - g1;
    const float c0 = constants[mj * kL + 0], c1 = constants[mj * kL + 1];
    const float gavg = 0.5f * (g0 + g1);
    float* base = sdp + m * 18;
    base[0 * 2 + j] = -(w0 * c0 * c0 + w1 * c1 * c1) * kInvLn2;  // An
    base[1 * 2 + j] = 2.f * w0 * c0 * kInvLn2;                   // B0n
    base[2 * 2 + j] = 2.f * w1 * c1 * kInvLn2;                   // B1n
    base[3 * 2 + j] = -w0 * kInvLn2;                             // w0n
    base[4 * 2 + j] = -w1 * kInvLn2;                             // w1n
#pragma unroll
    for (int l = 0; l < kL; ++l)
#pragma unroll
      for (int lp = 0; lp < kL; ++lp) {
        float acc = 0.f;
#pragma unroll
        for (int i = 0; i < kI; ++i)
          acc += W_head[(m * kL + l) * kI + i] * W_body[(mj * kI + i) * kL + lp];
        base[(5 + l * kL + lp) * 2 + j] = gavg * acc;            // C[l][lp]
      }
  } else if (t >= 64 && t < 68) {
    const int m = t - 64;
#pragma unroll
    for (int l = 0; l < kL; ++l) {
      float d = b_head[m * kL + l];
#pragma unroll
      for (int j = 0; j < kJ; ++j) {
        const int mj = m * kJ + j;
        const float g0 = fminf(fmaxf(gammas[mj * kL + 0], 0.f), 1.f);
        const float g1 = fminf(fmaxf(gammas[mj * kL + 1], 0.f), 1.f);
        const float gavg = 0.5f * (g0 + g1);
        float acc = 0.f;
#pragma unroll
        for (int i = 0; i < kI; ++i)
          acc += W_head[(m * kL + l) * kI + i] * b_body[mj * kI + i];
        d += gavg * acc;
      }
      sdp[72 + m * kL + l] = d;
    }
  }
  __syncthreads();

  float Cs = 0.f, X0 = 0.f, X1 = 0.f, K = 0.f;

#pragma unroll 1   // one m's params live at a time (VGPR <= 64, no spill)
  for (int m = 0; m < kM; ++m) {
    const float* P = sdp + m * 18;
    v2f An  = *reinterpret_cast<const v2f*>(P + 0);
    v2f B0n = *reinterpret_cast<const v2f*>(P + 2);
    v2f B1n = *reinterpret_cast<const v2f*>(P + 4);
    const v2f w0n = *reinterpret_cast<const v2f*>(P + 6);
    const v2f w1n = *reinterpret_cast<const v2f*>(P + 8);
    // Force addends into VGPRs: each pk op below then reads at most ONE
    // scalar (SGPR) operand -> legal VOP3P -> true v_pk_fma_f32 emission.
    asm volatile("" : "+v"(An), "+v"(B0n), "+v"(B1n));

    v2f psum = {1e-35f, 1e-35f};   // guard: rcp never sees denormal/0
    v2f pb0 = {0.f, 0.f}, pb1 = {0.f, 0.f}, pmq = {0.f, 0.f};
#pragma unroll
    for (int w = 0; w < kW; ++w) {
      const float sx = s[w].x, sy = s[w].y;
      v2f t0 = B0n + w0n * sx;       // pk_fma: sgpr=w0n, vgpr addend
      v2f t1 = B1n + w1n * sy;       // pk_fma: sgpr=w1n
      v2f msN = An + t0 * sx;        // pk_fma: all-vgpr
      msN += t1 * sy;                // pk_fma: all-vgpr
      v2f e; e.x = fexp2(msN.x); e.y = fexp2(msN.y);
      psum += e;                     // pk_add
      pb0 += e * sx;                 // pk_fma
      pb1 += e * sy;                 // pk_fma
      pmq += e * msN;                // pk_fma  ( = -Σ e·ms/ln2 )
    }

    v2f rinv;
    rinv.x = __builtin_amdgcn_rcpf(psum.x);
    rinv.y = __builtin_amdgcn_rcpf(psum.y);
    const v2f bb0 = pb0 * rinv, bb1 = pb1 * rinv;
    const v2f mqv = pmq * rinv;
    const float conf = fexp2(mqv.x + mqv.y);   // exp2(-mq/ln2) = exp(-mq)

    const v2f C00 = *reinterpret_cast<const v2f*>(P + 10);
    const v2f C01 = *reinterpret_cast<const v2f*>(P + 12);
    const v2f C10 = *reinterpret_cast<const v2f*>(P + 14);
    const v2f C11 = *reinterpret_cast<const v2f*>(P + 16);
    v2f u0 = C00 * bb0;              // pk_mul: 1 sgpr — legal
    u0 += C01 * bb1;                 // pk_fma: 1 sgpr — legal
    v2f u1 = C10 * bb0;
    u1 += C11 * bb1;
    const float r0 = sdp[72 + m * 2 + 0] + u0.x + u0.y;
    const float r1 = sdp[72 + m * 2 + 1] + u1.x + u1.y;

    Cs += conf;
    X0 = fmaf(conf, r0, X0);
    X1 = fmaf(conf, r1, X1);
    K = fmaf(conf, fmaf(r0, r0, r1 * r1), K);
  }

  const float X02 = 2.f * X0, X12 = 2.f * X1;
  float* orow = out + (size_t)b * kW;
#pragma unroll
  for (int w = 0; w < kW; ++w) {
    const v2f q = s[w] * s[w];
    // out = 2X0*s0 + 2X1*s1 - Cs*(s0^2+s1^2) - K
    orow[w] = fmaf(X02, s[w].x, fmaf(X12, s[w].y, fmaf(-Cs, q.x + q.y, -K)));
  }
}
}  // namespace

extern "C" void kernel_launch(void* const* d_in, const int* in_sizes, int n_in,
                              void* d_out, int out_size, void* d_ws, size_t ws_size,
                              hipStream_t stream) {
  const float* state     = (const float*)d_in[0];
  const float* constants = (const float*)d_in[1];
  const float* gammas    = (const float*)d_in[2];
  const float* W_body    = (const float*)d_in[3];
  const float* b_body    = (const float*)d_in[4];
  const float* W_head    = (const float*)d_in[5];
  const float* b_head    = (const float*)d_in[6];
  float* out = (float*)d_out;

  const int B = in_sizes[0] / (kW * kL);   // 1048576
  hipLaunchKernelGGL(algelogic_one, dim3(B / 256), dim3(256), 0, stream,
                     state, constants, gammas, W_body, b_body, W_head, b_head, out);
}